// Round 5
// baseline (207.839 us; speedup 1.0000x reference)
//
#include <hip/hip_runtime.h>
#include <math.h>

// DSHW — R11: R9 two-kernel structure + compile-time phases + cheaper recips.
//   * Two kernels again (R10 fusion regressed: epilogue serialized on the
//     starved scan threads; total-minus-kernel ~58-61us is harness-fixed).
//   * Scan restructured: group0(24) + 2 x supergroup(168) + run144 + tail8.
//     All ring indices and sW phases are compile-time -> no i2r/i2w SALU,
//     LDS accesses = base + offset-immediate.
//   * D-stage reciprocal = raw v_rcp_f64 (~2^-26; enters only gamma/omega-
//     damped multiplicative Ic/wc updates -> ~1e-7 rel, << f32 ref noise).
//     B keeps 1-NR (feeds u -> s-chain). Init keeps 2-NR.
//   * aur-only ring (uring dropped): D consumes x = aur/snew with ga/al,
//     om/al folded coefficients.
// Pipeline at iteration j (step s): C serial core; A LDS-reads (s+12);
// B recip for step s+4; D recip + Ic/wc update for step s-2.

#define P1c   24
#define P2c   168
#define NSTEP 512
#define BSc   64
#define NFc   16
#define MAXH  336
#define NT    32
#define NSERIES 1024

#define OFF_FC   0
#define OFF_YH   (BSc * MAXH * NFc)
#define OFF_E    (OFF_YH + BSc * NSTEP * NFc)
#define OFF_IC   (OFF_E  + BSc * NSTEP * NFc)
#define OFF_WC   (OFF_IC + BSc * P1c * NFc)
#define OFF_T    (OFF_WC + BSc * P2c * NFc)
#define OFF_S    (OFF_T  + BSc * NFc)

#define WS_NEED ((size_t)194 * NSERIES * sizeof(double))

__device__ __forceinline__ double nrcp(double a) {      // 2-NR (init only)
    double x = __builtin_amdgcn_rcp(a);
    x = fma(fma(-a, x, 1.0), x, x);
    x = fma(fma(-a, x, 1.0), x, x);
    return x;
}

__device__ __forceinline__ double nrcp1(double a) {     // 1-NR (B stage)
    double x = __builtin_amdgcn_rcp(a);
    x = fma(fma(-a, x, 1.0), x, x);
    return x;
}

__global__ __launch_bounds__(NT, 1)
void dshw_scan4(const float* __restrict__ y,
                const float* __restrict__ alphas,
                const float* __restrict__ betas,
                const float* __restrict__ gammas,
                const float* __restrict__ omegas,
                double* __restrict__ wsst,
                float* __restrict__ out)
{
    __shared__ double sW[P2c][NT];                    // 42 KiB
    __shared__ __align__(16) float sY[NSTEP][NT];     // 64 KiB (y -> yhat)

    const int tid = threadIdx.x;
    const int g   = blockIdx.x * NT + tid;
    const int f   = g & 15;

    // ---------------- stage y into LDS (coalesced) ----------------
    const float4* __restrict__ y4 =
        (const float4*)(y + (size_t)(blockIdx.x * 2) * NSTEP * NFc);
    #pragma unroll 8
    for (int i = tid; i < (NSTEP * NT) / 4; i += NT) {
        float4 v = y4[i];
        const int e0 = i << 2;            // element index in 2-batch chunk
        const int f0 = e0 & 15;           // feature (multiple of 4)
        const int r  = e0 >> 4;           // bl*512 + step
        const int st = r & (NSTEP - 1);
        const int bl = r >> 9;
        *(float4*)&sY[st][bl * 16 + f0] = v;
    }
    __syncthreads();

    const double al = 1.0 / (1.0 + exp(-(double)alphas[f]));
    const double be = 1.0 / (1.0 + exp(-(double)betas[f]));
    const double ga = 1.0 / (1.0 + exp(-(double)gammas[f]));
    const double om = 1.0 / (1.0 + exp(-(double)omegas[f]));
    const double one_m_al = 1.0 - al, one_m_be = 1.0 - be;
    const double one_p_be = 1.0 + be;
    const double one_m_ga = 1.0 - ga, one_m_om = 1.0 - om;
    const double inv_al = nrcp(al);
    const double ga_al  = ga * inv_al;    // D consumes aur = al*u
    const double om_al  = om * inv_al;

    // ---------------- init (all LDS reads, own column) ----------------
    double Icr[P1c];
    double sum48 = 0.0;
    #pragma unroll
    for (int ph = 0; ph < P1c; ++ph) {
        double v0 = (double)sY[ph][tid];
        double v1 = (double)sY[ph + P1c][tid];
        Icr[ph] = 0.5 * (v0 + v1);
        sum48 += v0 + v1;
    }
    const double inv_mean48 = 48.0 * nrcp(sum48);
    #pragma unroll
    for (int ph = 0; ph < P1c; ++ph) Icr[ph] *= inv_mean48;

    double sa = 0.0, sb = 0.0;
    #pragma unroll 8
    for (int i = 0; i < P2c; ++i) {
        double v0 = (double)sY[i][tid];
        double v1 = (double)sY[i + P2c][tid];
        sW[i][tid] = 0.5 * (v0 + v1);
        sa += v0; sb += v1;
    }
    const double mean336     = (sa + sb) * (1.0 / 336.0);
    const double inv_mean336 = nrcp(mean336);
    #pragma unroll
    for (int ph = 0; ph < P1c; ++ph) {
        double rI = inv_mean336 * nrcp(Icr[ph]);
        #pragma unroll
        for (int r = 0; r < 7; ++r) {
            const int i = ph + 24 * r;
            sW[i][tid] = sW[i][tid] * rI;
        }
    }

    double tt0 = 0.5 * ((sa - sb) * (1.0 / (168.0 * 168.0)) +
                        ((double)sY[P2c - 1][tid] - (double)sY[0][tid]) * (1.0 / 168.0));
    double ss0 = mean336 - 168.5 * tt0;

    // serial-core carried state: spt_k and sprev = snew_{k-1}
    double spt   = ss0 + tt0;
    double sprev = ss0;

    // ---------------- scan ----------------
    double yring[12], wring[24], aring[8], iwring[6], snring[3];

    #pragma unroll
    for (int k = 0; k < 12; ++k) yring[k] = (double)sY[k][tid];
    #pragma unroll
    for (int k = 0; k < 12; ++k) wring[k] = sW[k][tid];
    // B warmup: steps 0..3 (2-NR here, off-loop)
    #pragma unroll
    for (int m = 0; m < 4; ++m) {
        double iw  = Icr[m] * wring[m];
        double inv = nrcp(iw);
        iwring[m % 6] = iw;
        aring[m % 8]  = (al * yring[m % 12]) * inv;
    }

    // One step body. All index expressions compile-time after full unroll.
    //   S_ROW  : sY row of step s (compile-time when base is constexpr)
    //   J      : ring index source (== s mod 24-multiple)
    //   PH_R   : sW read phase  = (s+12) % 168
    //   PH_W   : sW write phase = (s-2) % 168
#define STEP_C(S_ROW, J)                                                     \
    {                                                                        \
        double snew = fma(one_m_al, spt, aring[(J) % 8]);                    \
        double h    = fma(one_m_be, spt, -sprev);                            \
        double yhat = spt * iwring[(J) % 6];                                 \
        double sptn = fma(one_p_be, snew, h);                                \
        sY[S_ROW][tid] = (float)yhat;                                        \
        snring[(J) % 3] = snew;                                              \
        sprev = snew; spt = sptn;                                            \
    }
#define STEP_A(S_ROW12, J, PH_R)                                             \
    {                                                                        \
        wring[((J) + 12) % 24] = sW[PH_R][tid];                              \
        yring[(J) % 12] = (double)sY[S_ROW12][tid];                          \
    }
#define STEP_B(J)                                                            \
    {                                                                        \
        double iw2  = Icr[((J) + 4) % 24] * wring[((J) + 4) % 24];           \
        double inv2 = nrcp1(iw2);                                            \
        iwring[((J) + 4) % 6] = iw2;                                         \
        aring[((J) + 4) % 8]  = (al * yring[((J) + 4) % 12]) * inv2;         \
    }
#define STEP_D(J, PH_W)                                                      \
    {                                                                        \
        double r   = __builtin_amdgcn_rcp(snring[((J) + 1) % 3]);            \
        double x   = aring[((J) + 6) % 8] * r;                               \
        double icO = Icr[((J) + 22) % 24];                                   \
        double wcO = wring[((J) + 22) % 24];                                 \
        Icr[((J) + 22) % 24] = icO * fma(ga_al, x, one_m_ga);                \
        sW[PH_W][tid] = wcO * fma(om_al, x, one_m_om);                       \
    }

    // ---- group 0: s = 0..23 (D guarded for j < 2) ----
    #pragma unroll
    for (int j = 0; j < 24; ++j) {
        STEP_C(j, j)
        STEP_A(j + 12, j, (12 + j))
        STEP_B(j)
        if (j >= 2) STEP_D(j, (j - 2))
    }

    // ---- supergroups: s = 24..191, 192..359 (phases repeat mod 168) ----
    for (int k = 0; k < 2; ++k) {
        const int sbse = 24 + 168 * k;
        #pragma unroll
        for (int j = 0; j < 168; ++j) {
            STEP_C(sbse + j, j)
            STEP_A(sbse + j + 12, j, ((36 + j) % 168))
            STEP_B(j)
            STEP_D(j, ((22 + j) % 168))
        }
    }

    // ---- run144: s = 360..503 (constexpr base; clamp A for j >= 140) ----
    #pragma unroll
    for (int j = 0; j < 144; ++j) {
        STEP_C(360 + j, j)
        {
            const int pr = (36 + j) % 168;
            const int row12 = (360 + j + 12 < NSTEP) ? (360 + j + 12) : (NSTEP - 1);
            STEP_A(row12, j, pr)
        }
        STEP_B(j)
        STEP_D(j, ((22 + j) % 168))
    }

    // ---- tail: s = 504..511 (no A; B for j < 4; D for steps 502..509) ----
    #pragma unroll
    for (int j = 0; j < 8; ++j) {
        STEP_C(504 + j, j)
        if (j < 4) STEP_B(j)
        STEP_D(j, ((166 + j) % 168))
    }
    // drain D: step 510 (virtual j=8, phase 4), step 511 (virtual j=9, phase 5)
    STEP_D(8, 4)
    STEP_D(9, 5)

#undef STEP_C
#undef STEP_A
#undef STEP_B
#undef STEP_D

    // reconstruct (ss, tt)
    const double ss_f = sprev;          // snew_511
    const double tt_f = spt - sprev;    // tnew_511

    // dump raw f64 state, item-major (lanes -> consecutive series)
    #pragma unroll
    for (int p = 0; p < P1c; ++p)  wsst[(size_t)p * NSERIES + g] = Icr[p];
    #pragma unroll 8
    for (int p = 0; p < P2c; ++p)  wsst[(size_t)(P1c + p) * NSERIES + g] = sW[p][tid];
    wsst[(size_t)192 * NSERIES + g] = ss_f;
    wsst[(size_t)193 * NSERIES + g] = tt_f;

    {
        const int bb = g >> 4;
        out[OFF_T + bb * NFc + f] = (float)tt_f;
        out[OFF_S + bb * NFc + f] = (float)ss_f;
    }

    // ---------------- coalesced yhat flush ----------------
    __syncthreads();
    float* __restrict__ yho = out + OFF_YH + (size_t)(blockIdx.x * 2) * NSTEP * NFc;
    #pragma unroll 8
    for (int i = tid; i < (NSTEP * NT) / 4; i += NT) {
        const int e0 = i << 2;
        const int f0 = e0 & 15;
        const int r  = e0 >> 4;
        const int st = r & (NSTEP - 1);
        const int bl = r >> 9;
        float4 v = *(const float4*)&sY[st][bl * 16 + f0];
        ((float4*)yho)[i] = v;
    }
}

// ---------------------------------------------------------------------------
// Kernel 2: parallel epilogue — fcast + rolled Ic/wc + e = y - yhat.
// item space per bb: [0,336) fc | [336,360) Ic | [360,528) wc | [528,1040) e
// ---------------------------------------------------------------------------
__global__ __launch_bounds__(256)
void dshw_epilogue(const double* __restrict__ ws,
                   const float* __restrict__ yin,
                   float* __restrict__ out)
{
    const int f      = threadIdx.x & 15;
    const int isub   = threadIdx.x >> 4;
    const int bb     = blockIdx.x & 63;
    const int chunk  = blockIdx.x >> 6;
    const int item   = chunk * 16 + isub;
    const int series = bb * NFc + f;

    if (item < MAXH) {
        const int k = item;
        double cb = ws[(size_t)((k + 8) % P1c) * NSERIES + series];
        double cc = ws[(size_t)(P1c + (k + 8) % P2c) * NSERIES + series];
        double ss = ws[(size_t)192 * NSERIES + series];
        double tt = ws[(size_t)193 * NSERIES + series];
        double ca = ss + (double)(k + 1) * tt;
        out[OFF_FC + (bb * MAXH + k) * NFc + f] = (float)(ca * cb * cc);
    } else if (item < MAXH + P1c) {
        const int j = item - MAXH;
        out[OFF_IC + (bb * P1c + j) * NFc + f] =
            (float)ws[(size_t)((j + 8) % P1c) * NSERIES + series];
    } else if (item < MAXH + P1c + P2c) {
        const int j = item - (MAXH + P1c);
        out[OFF_WC + (bb * P2c + j) * NFc + f] =
            (float)ws[(size_t)(P1c + (j + 8) % P2c) * NSERIES + series];
    } else {
        const int s = item - (MAXH + P1c + P2c);       // [0, 512)
        const size_t off = ((size_t)bb * NSTEP + s) * NFc + f;
        float yv = yin[off];
        float yh = out[OFF_YH + off];
        out[OFF_E + off] = yv - yh;
    }
}

// ---------------------------------------------------------------------------
// Fallback (R2 fused kernel, verbatim) — used only if ws is too small.
// ---------------------------------------------------------------------------
__global__ __launch_bounds__(NT, 1)
void dshw_fused(const float* __restrict__ y,
                const float* __restrict__ alphas,
                const float* __restrict__ betas,
                const float* __restrict__ gammas,
                const float* __restrict__ omegas,
                float* __restrict__ out)
{
    __shared__ double sIc[P1c][NT];
    __shared__ double sWc[P2c][NT];

    const int tid = threadIdx.x;
    const int g   = blockIdx.x * NT + tid;
    const int bb  = g >> 4;
    const int f   = g & 15;

    const float* __restrict__ yb = y + (size_t)bb * NSTEP * NFc + f;

    const double al = 1.0 / (1.0 + exp(-(double)alphas[f]));
    const double be = 1.0 / (1.0 + exp(-(double)betas[f]));
    const double ga = 1.0 / (1.0 + exp(-(double)gammas[f]));
    const double om = 1.0 / (1.0 + exp(-(double)omegas[f]));

    double sum48 = 0.0;
    #pragma unroll
    for (int ph = 0; ph < P1c; ++ph) {
        double v0 = (double)yb[ph * NFc];
        double v1 = (double)yb[(ph + P1c) * NFc];
        sIc[ph][tid] = 0.5 * (v0 + v1);
        sum48 += v0 + v1;
    }
    const double inv_mean48 = 48.0 / sum48;
    #pragma unroll
    for (int ph = 0; ph < P1c; ++ph) sIc[ph][tid] *= inv_mean48;

    double sum168a = 0.0, sum168b = 0.0;
    for (int i = 0; i < P2c; ++i) {
        double v0 = (double)yb[i * NFc];
        double v1 = (double)yb[(i + P2c) * NFc];
        sWc[i][tid] = 0.5 * (v0 + v1);
        sum168a += v0;
        sum168b += v1;
    }
    const double mean336 = (sum168a + sum168b) * (1.0 / 336.0);
    for (int i = 0; i < P2c; ++i) {
        sWc[i][tid] = (sWc[i][tid] / mean336) / sIc[i % P1c][tid];
    }

    double tt = 0.5 * ((sum168a - sum168b) * (1.0 / (168.0 * 168.0)) +
                       ((double)yb[(P2c - 1) * NFc] - (double)yb[0]) * (1.0 / 168.0));
    double ss = mean336 - 168.5 * tt;

    float* __restrict__ yh_o = out + OFF_YH + (size_t)bb * NSTEP * NFc + f;
    float* __restrict__ e_o  = out + OFF_E  + (size_t)bb * NSTEP * NFc + f;

    int i1 = 0, i2 = 0;
    int i1p = 2, i2p = 2;

    double Icv0 = sIc[0][tid], Icv1 = sIc[1][tid];
    double wcv0 = sWc[0][tid], wcv1 = sWc[1][tid];
    double yt0 = (double)yb[0 * NFc], yt1 = (double)yb[1 * NFc];
    double yt2 = (double)yb[2 * NFc], yt3 = (double)yb[3 * NFc];

    #pragma unroll 4
    for (int step = 0; step < NSTEP; ++step) {
        double Icv2 = sIc[i1p][tid];
        double wcv2 = sWc[i2p][tid];
        int    pidx = step + 4; pidx = (pidx < NSTEP) ? pidx : (NSTEP - 1);
        double yt4  = (double)yb[pidx * NFc];

        double iw     = Icv0 * wcv0;
        double spt    = ss + tt;
        double yhat   = spt * iw;
        double inv_iw = 1.0 / iw;
        double u      = yt0 * inv_iw;
        double snew   = al * u + (1.0 - al) * spt;
        double tnew   = be * (snew - ss) + (1.0 - be) * tt;
        double q      = yt0 / snew;
        double icn    = ga * (q * (inv_iw * Icv0)) + (1.0 - ga) * Icv0;
        double wcn    = om * (q * (inv_iw * wcv0)) + (1.0 - om) * wcv0;

        sIc[i1][tid] = icn;
        sWc[i2][tid] = wcn;
        yh_o[step * NFc] = (float)yhat;
        e_o[step * NFc]  = (float)(yt0 - yhat);

        ss = snew; tt = tnew;
        Icv0 = Icv1; Icv1 = Icv2;
        wcv0 = wcv1; wcv1 = wcv2;
        yt0 = yt1; yt1 = yt2; yt2 = yt3; yt3 = yt4;
        i1  = (i1  + 1 == P1c) ? 0 : i1  + 1;
        i2  = (i2  + 1 == P2c) ? 0 : i2  + 1;
        i1p = (i1p + 1 == P1c) ? 0 : i1p + 1;
        i2p = (i2p + 1 == P2c) ? 0 : i2p + 1;
    }

    float* __restrict__ fc_o = out + OFF_FC + (size_t)bb * MAXH * NFc + f;
    {
        int k1 = 8, k2 = 8;
        for (int k = 0; k < MAXH; ++k) {
            double cb = sIc[k1][tid];
            double cc = sWc[k2][tid];
            double ca = ss + (double)(k + 1) * tt;
            fc_o[k * NFc] = (float)(ca * cb * cc);
            k1 = (k1 + 1 == P1c) ? 0 : k1 + 1;
            k2 = (k2 + 1 == P2c) ? 0 : k2 + 1;
        }
    }
    {
        float* __restrict__ ic_o = out + OFF_IC + (size_t)bb * P1c * NFc + f;
        int k1 = 8;
        #pragma unroll
        for (int j = 0; j < P1c; ++j) {
            ic_o[j * NFc] = (float)sIc[k1][tid];
            k1 = (k1 + 1 == P1c) ? 0 : k1 + 1;
        }
    }
    {
        float* __restrict__ wc_o = out + OFF_WC + (size_t)bb * P2c * NFc + f;
        int k2 = 8;
        for (int j = 0; j < P2c; ++j) {
            wc_o[j * NFc] = (float)sWc[k2][tid];
            k2 = (k2 + 1 == P2c) ? 0 : k2 + 1;
        }
    }

    out[OFF_T + bb * NFc + f] = (float)tt;
    out[OFF_S + bb * NFc + f] = (float)ss;
}

extern "C" void kernel_launch(void* const* d_in, const int* in_sizes, int n_in,
                              void* d_out, int out_size, void* d_ws, size_t ws_size,
                              hipStream_t stream)
{
    const float* y      = (const float*)d_in[0];
    const float* alphas = (const float*)d_in[1];
    const float* betas  = (const float*)d_in[2];
    const float* gammas = (const float*)d_in[3];
    const float* omegas = (const float*)d_in[4];
    float* out = (float*)d_out;

    if (ws_size >= WS_NEED) {
        double* wsst = (double*)d_ws;
        hipLaunchKernelGGL(dshw_scan4, dim3(NSERIES / NT), dim3(NT), 0, stream,
                           y, alphas, betas, gammas, omegas, wsst, out);
        hipLaunchKernelGGL(dshw_epilogue, dim3(65 * BSc), dim3(256), 0, stream,
                           wsst, y, out);
    } else {
        hipLaunchKernelGGL(dshw_fused, dim3(NSERIES / NT), dim3(NT), 0, stream,
                           y, alphas, betas, gammas, omegas, out);
    }
}

// Round 6
// 134.478 us; speedup vs baseline: 1.5455x; 1.5455x over previous
//
#include <hip/hip_runtime.h>
#include <math.h>

// DSHW — R12: window-linearized scan, W=8.
//   The (spt,snp) recurrence is LTI given aur_k = al*u_k, and u_k needs only
//   Ic (updated >=24 steps earlier) / wc (>=168 earlier). Per 8-step window:
//     phase L: 8 wc + 8 y LDS loads (issued first)
//     phase D': deferred Ic/wc updates of the PREVIOUS window (covers load lat)
//     phase 1: 8 independent aur_j = al*y_j/(Ic_j*wc_j)   (parallel rcps)
//     phase 2: spt_j = P_j*spt0 + Q_j*snp0 + sum R_{j-1-i}*aur_i  (precomputed
//              impulse-response coeffs; ~50 independent FMAs)
//     phase 3: yhat_j = spt_j*iw_j -> sY; x_j = aur_j/snew_j saved for D'
//   Serial cross-window path ~10 dependent ops per 8 steps (was ~230 cyc
//   stall/step). Loop = 10 superstep-pairs, code ~15 KB (R11 lesson: I-cache).
// R11 post-mortem: full unroll blew I-cache (FETCH +674 KB, VALUBusy 0.66%).
// Predicted: scan 77.5 -> ~35-45 us, total -> ~100-110. Watch VGPR_Count==256
// (spill) and FETCH_SIZE jump (code size) as failure signatures.

#define P1c   24
#define P2c   168
#define NSTEP 512
#define BSc   64
#define NFc   16
#define MAXH  336
#define NT    32
#define NSERIES 1024

#define OFF_FC   0
#define OFF_YH   (BSc * MAXH * NFc)
#define OFF_E    (OFF_YH + BSc * NSTEP * NFc)
#define OFF_IC   (OFF_E  + BSc * NSTEP * NFc)
#define OFF_WC   (OFF_IC + BSc * P1c * NFc)
#define OFF_T    (OFF_WC + BSc * P2c * NFc)
#define OFF_S    (OFF_T  + BSc * NFc)

#define WS_NEED ((size_t)194 * NSERIES * sizeof(double))

__device__ __forceinline__ double nrcp(double a) {      // 2-NR (init only)
    double x = __builtin_amdgcn_rcp(a);
    x = fma(fma(-a, x, 1.0), x, x);
    x = fma(fma(-a, x, 1.0), x, x);
    return x;
}

__device__ __forceinline__ double nrcp1(double a) {     // 1-NR (loop)
    double x = __builtin_amdgcn_rcp(a);
    x = fma(fma(-a, x, 1.0), x, x);
    return x;
}

// one 8-step window; O/PO/PAR/HASD compile-time so Icr/wcvS indices fold.
template<int O, int PO, int PAR, bool HASD>
__device__ __forceinline__ void window8(
    double (&Icr)[P1c], double (&wcvS)[2][8], double (&xP)[8],
    const double (&Pc)[9], const double (&Qc)[9], const double (&Rc)[8],
    double &spt0, double &snp0, int &Kb, int &wrow, int &prow,
    double al, double one_m_al, double ga_al, double one_m_ga,
    double om_al, double one_m_om,
    float (*sY)[NT], double (*sW)[NT], int tid)
{
    // phase L: issue current-window loads
    float yv[8];
    #pragma unroll
    for (int j = 0; j < 8; ++j) wcvS[PAR][j] = sW[wrow + j][tid];
    #pragma unroll
    for (int j = 0; j < 8; ++j) yv[j] = sY[Kb + j][tid];

    // phase D': deferred Ic/wc updates of previous window (disjoint Icr range,
    // disjoint sW rows; issue covers the load latency above)
    if (HASD) {
        #pragma unroll
        for (int j = 0; j < 8; ++j) {
            double xx = xP[j];
            Icr[PO + j] = Icr[PO + j] * fma(ga_al, xx, one_m_ga);
            sW[prow + j][tid] = wcvS[1 - PAR][j] * fma(om_al, xx, one_m_om);
        }
    }

    // phase 1: parallel aur
    double iw[8], aur[8];
    #pragma unroll
    for (int j = 0; j < 8; ++j) {
        double w   = wcvS[PAR][j];
        double iwj = Icr[O + j] * w;
        iw[j]  = iwj;
        double inv = nrcp1(iwj);
        aur[j] = (al * (double)yv[j]) * inv;
    }

    // phase 2: linearized spt_j
    double sj[9];
    sj[0] = spt0;
    #pragma unroll
    for (int j = 1; j <= 8; ++j) {
        double acc = fma(Pc[j], spt0, Qc[j] * snp0);
        #pragma unroll
        for (int i = 0; i < j; ++i) acc = fma(Rc[j - 1 - i], aur[i], acc);
        sj[j] = acc;
    }
    double snew7 = fma(one_m_al, sj[7], aur[7]);

    // phase 3: yhat out + x for deferred D
    #pragma unroll
    for (int j = 0; j < 8; ++j) {
        sY[Kb + j][tid] = (float)(sj[j] * iw[j]);
        double snw = fma(one_m_al, sj[j], aur[j]);
        xP[j] = aur[j] * nrcp1(snw);
    }

    spt0 = sj[8];
    snp0 = snew7;
    prow = wrow;
    wrow = (wrow + 8 == P2c) ? 0 : (wrow + 8);
    Kb  += 8;
}

__global__ __launch_bounds__(NT, 1)
void dshw_scan4(const float* __restrict__ y,
                const float* __restrict__ alphas,
                const float* __restrict__ betas,
                const float* __restrict__ gammas,
                const float* __restrict__ omegas,
                double* __restrict__ wsst,
                float* __restrict__ out)
{
    __shared__ double sW[P2c][NT];                    // 42 KiB
    __shared__ __align__(16) float sY[NSTEP][NT];     // 64 KiB (y -> yhat)

    const int tid = threadIdx.x;
    const int g   = blockIdx.x * NT + tid;
    const int f   = g & 15;

    // ---------------- stage y into LDS (coalesced) ----------------
    const float4* __restrict__ y4 =
        (const float4*)(y + (size_t)(blockIdx.x * 2) * NSTEP * NFc);
    #pragma unroll 8
    for (int i = tid; i < (NSTEP * NT) / 4; i += NT) {
        float4 v = y4[i];
        const int e0 = i << 2;
        const int f0 = e0 & 15;
        const int r  = e0 >> 4;
        const int st = r & (NSTEP - 1);
        const int bl = r >> 9;
        *(float4*)&sY[st][bl * 16 + f0] = v;
    }
    __syncthreads();

    const double al = 1.0 / (1.0 + exp(-(double)alphas[f]));
    const double be = 1.0 / (1.0 + exp(-(double)betas[f]));
    const double ga = 1.0 / (1.0 + exp(-(double)gammas[f]));
    const double om = 1.0 / (1.0 + exp(-(double)omegas[f]));
    const double one_m_al = 1.0 - al, one_m_be = 1.0 - be;
    const double one_p_be = 1.0 + be;
    const double one_m_ga = 1.0 - ga, one_m_om = 1.0 - om;
    const double inv_al = nrcp(al);
    const double ga_al  = ga * inv_al;
    const double om_al  = om * inv_al;

    // ---------------- init (all LDS reads, own column) ----------------
    double Icr[P1c];
    double sum48 = 0.0;
    #pragma unroll
    for (int ph = 0; ph < P1c; ++ph) {
        double v0 = (double)sY[ph][tid];
        double v1 = (double)sY[ph + P1c][tid];
        Icr[ph] = 0.5 * (v0 + v1);
        sum48 += v0 + v1;
    }
    const double inv_mean48 = 48.0 * nrcp(sum48);
    #pragma unroll
    for (int ph = 0; ph < P1c; ++ph) Icr[ph] *= inv_mean48;

    double sa = 0.0, sb = 0.0;
    #pragma unroll 8
    for (int i = 0; i < P2c; ++i) {
        double v0 = (double)sY[i][tid];
        double v1 = (double)sY[i + P2c][tid];
        sW[i][tid] = 0.5 * (v0 + v1);
        sa += v0; sb += v1;
    }
    const double mean336     = (sa + sb) * (1.0 / 336.0);
    const double inv_mean336 = nrcp(mean336);
    #pragma unroll
    for (int ph = 0; ph < P1c; ++ph) {
        double rI = inv_mean336 * nrcp(Icr[ph]);
        #pragma unroll
        for (int r = 0; r < 7; ++r) {
            const int i = ph + 24 * r;
            sW[i][tid] = sW[i][tid] * rI;
        }
    }

    double tt0 = 0.5 * ((sa - sb) * (1.0 / (168.0 * 168.0)) +
                        ((double)sY[P2c - 1][tid] - (double)sY[0][tid]) * (1.0 / 168.0));
    double ss0 = mean336 - 168.5 * tt0;

    double spt0 = ss0 + tt0;      // spt_0
    double snp0 = ss0;            // snew_{-1}

    // ---------------- window coefficients (impulse response of M) ----------
    const double A_ = one_p_be * one_m_al + one_m_be;
    double Pc[9], Qc[9], Rc[8];
    {
        double p = 1.0, q = 0.0, pn = 0.0, qn = 1.0;
        Pc[0] = 1.0; Qc[0] = 0.0;
        #pragma unroll
        for (int j = 0; j < 8; ++j) {
            double p2 = fma(A_, p, -pn);
            double q2 = fma(A_, q, -qn);
            pn = one_m_al * p; qn = one_m_al * q;
            p = p2; q = q2;
            Pc[j + 1] = p; Qc[j + 1] = q;
        }
        double r = one_p_be, rn = 1.0;
        Rc[0] = r;
        #pragma unroll
        for (int m = 1; m < 8; ++m) {
            double r2 = fma(A_, r, -rn);
            rn = one_m_al * r;
            r = r2;
            Rc[m] = r;
        }
    }

    // ---------------- windowed scan: 64 windows of 8 ----------------
    double wcvS[2][8], xP[8];
    int Kb = 0, wrow = 0, prow = 0;

#define WARGS Icr, wcvS, xP, Pc, Qc, Rc, spt0, snp0, Kb, wrow, prow, \
              al, one_m_al, ga_al, one_m_ga, om_al, one_m_om, sY, sW, tid

    // peeled first superstep: w0,w1,w2
    window8<0,  0, 0, false>(WARGS);
    window8<8,  0, 1, true >(WARGS);
    window8<16, 8, 0, true >(WARGS);

    // 10 superstep-pairs: windows w3..w62
    for (int sp = 0; sp < 10; ++sp) {
        window8<0, 16, 1, true>(WARGS);
        window8<8,  0, 0, true>(WARGS);
        window8<16, 8, 1, true>(WARGS);
        window8<0, 16, 0, true>(WARGS);
        window8<8,  0, 1, true>(WARGS);
        window8<16, 8, 0, true>(WARGS);
    }

    // final window w63 (steps 504..511)
    window8<0, 16, 1, true>(WARGS);
#undef WARGS

    // drain D of w63 (Icr base 0, parity 1, rows prow..prow+7)
    #pragma unroll
    for (int j = 0; j < 8; ++j) {
        double xx = xP[j];
        Icr[j] = Icr[j] * fma(ga_al, xx, one_m_ga);
        sW[prow + j][tid] = wcvS[1][j] * fma(om_al, xx, one_m_om);
    }

    // reconstruct (ss, tt)
    const double ss_f = snp0;           // snew_511
    const double tt_f = spt0 - snp0;    // tnew_511

    // dump raw f64 state, item-major (lanes -> consecutive series)
    #pragma unroll
    for (int p = 0; p < P1c; ++p)  wsst[(size_t)p * NSERIES + g] = Icr[p];
    #pragma unroll 8
    for (int p = 0; p < P2c; ++p)  wsst[(size_t)(P1c + p) * NSERIES + g] = sW[p][tid];
    wsst[(size_t)192 * NSERIES + g] = ss_f;
    wsst[(size_t)193 * NSERIES + g] = tt_f;

    {
        const int bb = g >> 4;
        out[OFF_T + bb * NFc + f] = (float)tt_f;
        out[OFF_S + bb * NFc + f] = (float)ss_f;
    }

    // ---------------- coalesced yhat flush ----------------
    __syncthreads();
    float* __restrict__ yho = out + OFF_YH + (size_t)(blockIdx.x * 2) * NSTEP * NFc;
    #pragma unroll 8
    for (int i = tid; i < (NSTEP * NT) / 4; i += NT) {
        const int e0 = i << 2;
        const int f0 = e0 & 15;
        const int r  = e0 >> 4;
        const int st = r & (NSTEP - 1);
        const int bl = r >> 9;
        float4 v = *(const float4*)&sY[st][bl * 16 + f0];
        ((float4*)yho)[i] = v;
    }
}

// ---------------------------------------------------------------------------
// Kernel 2: parallel epilogue — fcast + rolled Ic/wc + e = y - yhat.
// item space per bb: [0,336) fc | [336,360) Ic | [360,528) wc | [528,1040) e
// ---------------------------------------------------------------------------
__global__ __launch_bounds__(256)
void dshw_epilogue(const double* __restrict__ ws,
                   const float* __restrict__ yin,
                   float* __restrict__ out)
{
    const int f      = threadIdx.x & 15;
    const int isub   = threadIdx.x >> 4;
    const int bb     = blockIdx.x & 63;
    const int chunk  = blockIdx.x >> 6;
    const int item   = chunk * 16 + isub;
    const int series = bb * NFc + f;

    if (item < MAXH) {
        const int k = item;
        double cb = ws[(size_t)((k + 8) % P1c) * NSERIES + series];
        double cc = ws[(size_t)(P1c + (k + 8) % P2c) * NSERIES + series];
        double ss = ws[(size_t)192 * NSERIES + series];
        double tt = ws[(size_t)193 * NSERIES + series];
        double ca = ss + (double)(k + 1) * tt;
        out[OFF_FC + (bb * MAXH + k) * NFc + f] = (float)(ca * cb * cc);
    } else if (item < MAXH + P1c) {
        const int j = item - MAXH;
        out[OFF_IC + (bb * P1c + j) * NFc + f] =
            (float)ws[(size_t)((j + 8) % P1c) * NSERIES + series];
    } else if (item < MAXH + P1c + P2c) {
        const int j = item - (MAXH + P1c);
        out[OFF_WC + (bb * P2c + j) * NFc + f] =
            (float)ws[(size_t)(P1c + (j + 8) % P2c) * NSERIES + series];
    } else {
        const int s = item - (MAXH + P1c + P2c);       // [0, 512)
        const size_t off = ((size_t)bb * NSTEP + s) * NFc + f;
        float yv = yin[off];
        float yh = out[OFF_YH + off];
        out[OFF_E + off] = yv - yh;
    }
}

// ---------------------------------------------------------------------------
// Fallback (R2 fused kernel, verbatim) — used only if ws is too small.
// ---------------------------------------------------------------------------
__global__ __launch_bounds__(NT, 1)
void dshw_fused(const float* __restrict__ y,
                const float* __restrict__ alphas,
                const float* __restrict__ betas,
                const float* __restrict__ gammas,
                const float* __restrict__ omegas,
                float* __restrict__ out)
{
    __shared__ double sIc[P1c][NT];
    __shared__ double sWc[P2c][NT];

    const int tid = threadIdx.x;
    const int g   = blockIdx.x * NT + tid;
    const int bb  = g >> 4;
    const int f   = g & 15;

    const float* __restrict__ yb = y + (size_t)bb * NSTEP * NFc + f;

    const double al = 1.0 / (1.0 + exp(-(double)alphas[f]));
    const double be = 1.0 / (1.0 + exp(-(double)betas[f]));
    const double ga = 1.0 / (1.0 + exp(-(double)gammas[f]));
    const double om = 1.0 / (1.0 + exp(-(double)omegas[f]));

    double sum48 = 0.0;
    #pragma unroll
    for (int ph = 0; ph < P1c; ++ph) {
        double v0 = (double)yb[ph * NFc];
        double v1 = (double)yb[(ph + P1c) * NFc];
        sIc[ph][tid] = 0.5 * (v0 + v1);
        sum48 += v0 + v1;
    }
    const double inv_mean48 = 48.0 / sum48;
    #pragma unroll
    for (int ph = 0; ph < P1c; ++ph) sIc[ph][tid] *= inv_mean48;

    double sum168a = 0.0, sum168b = 0.0;
    for (int i = 0; i < P2c; ++i) {
        double v0 = (double)yb[i * NFc];
        double v1 = (double)yb[(i + P2c) * NFc];
        sWc[i][tid] = 0.5 * (v0 + v1);
        sum168a += v0;
        sum168b += v1;
    }
    const double mean336 = (sum168a + sum168b) * (1.0 / 336.0);
    for (int i = 0; i < P2c; ++i) {
        sWc[i][tid] = (sWc[i][tid] / mean336) / sIc[i % P1c][tid];
    }

    double tt = 0.5 * ((sum168a - sum168b) * (1.0 / (168.0 * 168.0)) +
                       ((double)yb[(P2c - 1) * NFc] - (double)yb[0]) * (1.0 / 168.0));
    double ss = mean336 - 168.5 * tt;

    float* __restrict__ yh_o = out + OFF_YH + (size_t)bb * NSTEP * NFc + f;
    float* __restrict__ e_o  = out + OFF_E  + (size_t)bb * NSTEP * NFc + f;

    int i1 = 0, i2 = 0;
    int i1p = 2, i2p = 2;

    double Icv0 = sIc[0][tid], Icv1 = sIc[1][tid];
    double wcv0 = sWc[0][tid], wcv1 = sWc[1][tid];
    double yt0 = (double)yb[0 * NFc], yt1 = (double)yb[1 * NFc];
    double yt2 = (double)yb[2 * NFc], yt3 = (double)yb[3 * NFc];

    #pragma unroll 4
    for (int step = 0; step < NSTEP; ++step) {
        double Icv2 = sIc[i1p][tid];
        double wcv2 = sWc[i2p][tid];
        int    pidx = step + 4; pidx = (pidx < NSTEP) ? pidx : (NSTEP - 1);
        double yt4  = (double)yb[pidx * NFc];

        double iw     = Icv0 * wcv0;
        double spt    = ss + tt;
        double yhat   = spt * iw;
        double inv_iw = 1.0 / iw;
        double u      = yt0 * inv_iw;
        double snew   = al * u + (1.0 - al) * spt;
        double tnew   = be * (snew - ss) + (1.0 - be) * tt;
        double q      = yt0 / snew;
        double icn    = ga * (q * (inv_iw * Icv0)) + (1.0 - ga) * Icv0;
        double wcn    = om * (q * (inv_iw * wcv0)) + (1.0 - om) * wcv0;

        sIc[i1][tid] = icn;
        sWc[i2][tid] = wcn;
        yh_o[step * NFc] = (float)yhat;
        e_o[step * NFc]  = (float)(yt0 - yhat);

        ss = snew; tt = tnew;
        Icv0 = Icv1; Icv1 = Icv2;
        wcv0 = wcv1; wcv1 = wcv2;
        yt0 = yt1; yt1 = yt2; yt2 = yt3; yt3 = yt4;
        i1  = (i1  + 1 == P1c) ? 0 : i1  + 1;
        i2  = (i2  + 1 == P2c) ? 0 : i2  + 1;
        i1p = (i1p + 1 == P1c) ? 0 : i1p + 1;
        i2p = (i2p + 1 == P2c) ? 0 : i2p + 1;
    }

    float* __restrict__ fc_o = out + OFF_FC + (size_t)bb * MAXH * NFc + f;
    {
        int k1 = 8, k2 = 8;
        for (int k = 0; k < MAXH; ++k) {
            double cb = sIc[k1][tid];
            double cc = sWc[k2][tid];
            double ca = ss + (double)(k + 1) * tt;
            fc_o[k * NFc] = (float)(ca * cb * cc);
            k1 = (k1 + 1 == P1c) ? 0 : k1 + 1;
            k2 = (k2 + 1 == P2c) ? 0 : k2 + 1;
        }
    }
    {
        float* __restrict__ ic_o = out + OFF_IC + (size_t)bb * P1c * NFc + f;
        int k1 = 8;
        #pragma unroll
        for (int j = 0; j < P1c; ++j) {
            ic_o[j * NFc] = (float)sIc[k1][tid];
            k1 = (k1 + 1 == P1c) ? 0 : k1 + 1;
        }
    }
    {
        float* __restrict__ wc_o = out + OFF_WC + (size_t)bb * P2c * NFc + f;
        int k2 = 8;
        for (int j = 0; j < P2c; ++j) {
            wc_o[j * NFc] = (float)sWc[k2][tid];
            k2 = (k2 + 1 == P2c) ? 0 : k2 + 1;
        }
    }

    out[OFF_T + bb * NFc + f] = (float)tt;
    out[OFF_S + bb * NFc + f] = (float)ss;
}

extern "C" void kernel_launch(void* const* d_in, const int* in_sizes, int n_in,
                              void* d_out, int out_size, void* d_ws, size_t ws_size,
                              hipStream_t stream)
{
    const float* y      = (const float*)d_in[0];
    const float* alphas = (const float*)d_in[1];
    const float* betas  = (const float*)d_in[2];
    const float* gammas = (const float*)d_in[3];
    const float* omegas = (const float*)d_in[4];
    float* out = (float*)d_out;

    if (ws_size >= WS_NEED) {
        double* wsst = (double*)d_ws;
        hipLaunchKernelGGL(dshw_scan4, dim3(NSERIES / NT), dim3(NT), 0, stream,
                           y, alphas, betas, gammas, omegas, wsst, out);
        hipLaunchKernelGGL(dshw_epilogue, dim3(65 * BSc), dim3(256), 0, stream,
                           wsst, y, out);
    } else {
        hipLaunchKernelGGL(dshw_fused, dim3(NSERIES / NT), dim3(NT), 0, stream,
                           y, alphas, betas, gammas, omegas, out);
    }
}

// Round 7
// 84.985 us; speedup vs baseline: 2.4456x; 1.5824x over previous
//
#include <hip/hip_runtime.h>
#include <math.h>

// DSHW — R13: 8-lanes-per-series window-parallel scan (W=8).
// Empirical law from R8/R9/R12: time ≈ instr/wave × ~11.5 cyc, independent of
// dependency structure. So: cut per-lane instruction count 4× by mapping each
// series to an 8-lane group; lane j owns step j of each 8-step window:
//   L: own wc row (ds_read_b64) + own y (ds_read_b32)
//   D': own Ic phase + own wc row update from previous window's x
//   p1: own aur = al*y/(Ic*wc)            (1 rcp chain per lane)
//   p2: sj[j] = Pl*spt0 + Ql*snp0 + sum cf[i]*bcast(aur, i)   (8 swizzles)
//   p3: yhat -> sY; x = aur * rcp(snew_j)
//   handoff: bcast s6,s7,a6,a7; all lanes recompute spt0' = spt8, snp0' = snew7
// Per-lane constants Pl/Ql/cf[] built once with compile-time-indexed selects.
// Block = 128 thr = 16 series = one batch row; 64 blocks. Same ws layout ->
// epilogue unchanged. Math identical to R12's (passed); x uses raw rcp (R11
// passed with that). Predicted: scan 72 -> 20-30us, total -> ~90-100us.

#define P1c   24
#define P2c   168
#define NSTEP 512
#define BSc   64
#define NFc   16
#define MAXH  336
#define NT    32
#define NSERIES 1024

#define OFF_FC   0
#define OFF_YH   (BSc * MAXH * NFc)
#define OFF_E    (OFF_YH + BSc * NSTEP * NFc)
#define OFF_IC   (OFF_E  + BSc * NSTEP * NFc)
#define OFF_WC   (OFF_IC + BSc * P1c * NFc)
#define OFF_T    (OFF_WC + BSc * P2c * NFc)
#define OFF_S    (OFF_T  + BSc * NFc)

#define WS_NEED ((size_t)194 * NSERIES * sizeof(double))

__device__ __forceinline__ double nrcp(double a) {      // 2-NR (init only)
    double x = __builtin_amdgcn_rcp(a);
    x = fma(fma(-a, x, 1.0), x, x);
    x = fma(fma(-a, x, 1.0), x, x);
    return x;
}

__device__ __forceinline__ double nrcp1(double a) {     // 1-NR (p1)
    double x = __builtin_amdgcn_rcp(a);
    x = fma(fma(-a, x, 1.0), x, x);
    return x;
}

// broadcast lane I (0..7) of each 8-lane group: BitMode and=0x18 or=I xor=0
template<int I>
__device__ __forceinline__ double bcast8(double v) {
    constexpr int pat = (I << 5) | 0x18;
    int lo = __builtin_amdgcn_ds_swizzle(__double2loint(v), pat);
    int hi = __builtin_amdgcn_ds_swizzle(__double2hiint(v), pat);
    return __hiloint2double(hi, lo);
}
// xor-butterfly within 8-lane group: and=0x1f or=0 xor=M
template<int M>
__device__ __forceinline__ double xor8(double v) {
    constexpr int pat = (M << 10) | 0x1f;
    int lo = __builtin_amdgcn_ds_swizzle(__double2loint(v), pat);
    int hi = __builtin_amdgcn_ds_swizzle(__double2hiint(v), pat);
    return __hiloint2double(hi, lo);
}

__global__ __launch_bounds__(128, 1)
void dshw_scanw(const float* __restrict__ y,
                const float* __restrict__ alphas,
                const float* __restrict__ betas,
                const float* __restrict__ gammas,
                const float* __restrict__ omegas,
                double* __restrict__ wsst,
                float* __restrict__ out)
{
    __shared__ double sW[P2c][NFc];                   // 21 KiB
    __shared__ __align__(16) float sY[NSTEP][NFc];    // 32 KiB (y -> yhat)

    const int tid   = threadIdx.x;
    const int s_loc = tid >> 3;          // 0..15  (feature / series-in-block)
    const int j     = tid & 7;           // lane within series group
    const int bb    = blockIdx.x;        // batch row
    const int f     = s_loc;
    const int g     = bb * NFc + s_loc;  // global series id

    // ---------------- stage y into LDS (fully coalesced) ----------------
    const float4* __restrict__ y4 =
        (const float4*)(y + (size_t)bb * NSTEP * NFc);
    #pragma unroll 4
    for (int i = tid; i < (NSTEP * NFc) / 4; i += 128) {
        float4 v = y4[i];
        *(float4*)&sY[i >> 2][(i & 3) * 4] = v;
    }
    __syncthreads();

    const double al = 1.0 / (1.0 + exp(-(double)alphas[f]));
    const double be = 1.0 / (1.0 + exp(-(double)betas[f]));
    const double ga = 1.0 / (1.0 + exp(-(double)gammas[f]));
    const double om = 1.0 / (1.0 + exp(-(double)omegas[f]));
    const double one_m_al = 1.0 - al, one_m_be = 1.0 - be;
    const double one_p_be = 1.0 + be;
    const double one_m_ga = 1.0 - ga, one_m_om = 1.0 - om;
    const double inv_al = nrcp(al);
    const double ga_al  = ga * inv_al;
    const double om_al  = om * inv_al;
    const double A_ = one_p_be * one_m_al + one_m_be;

    // ---------------- per-lane window coefficients ----------------
    // Pl = P[j], Ql = Q[j]; cf[i] = (i<j) ? R[j-1-i] : 0
    double Pl = (j == 0) ? 1.0 : 0.0;
    double Ql = 0.0;
    {
        double p = 1.0, q = 0.0, pn = 0.0, qn = 1.0;
        #pragma unroll
        for (int it = 1; it <= 7; ++it) {
            double p2 = fma(A_, p, -pn);
            double q2 = fma(A_, q, -qn);
            pn = one_m_al * p; qn = one_m_al * q;
            p = p2; q = q2;
            if (j == it) { Pl = p; Ql = q; }
        }
    }
    double R_[8];
    R_[0] = one_p_be;
    {
        double r = one_p_be, rn = 1.0;
        #pragma unroll
        for (int m = 1; m < 8; ++m) {
            double r2 = fma(A_, r, -rn);
            rn = one_m_al * r;
            r = r2;
            R_[m] = r;
        }
    }
    double cf[8];
    #pragma unroll
    for (int i = 0; i < 8; ++i) cf[i] = 0.0;
    #pragma unroll
    for (int i = 0; i < 7; ++i) {
        #pragma unroll
        for (int m = 0; m + i + 1 <= 7; ++m) {
            if (j == i + m + 1) cf[i] = R_[m];
        }
    }

    // ---------------- init (lane-parallel sums + group reduce) -------------
    double pa = 0.0, pb = 0.0;
    #pragma unroll
    for (int m = 0; m < 21; ++m) {
        pa += (double)sY[j + 8 * m][s_loc];
        pb += (double)sY[j + 8 * m + P2c][s_loc];
    }
    pa += xor8<1>(pa); pb += xor8<1>(pb);
    pa += xor8<2>(pa); pb += xor8<2>(pb);
    pa += xor8<4>(pa); pb += xor8<4>(pb);
    const double sa = pa, sb = pb;

    double Icr_own[3];
    {
        double icv[3];
        double pc = 0.0;
        #pragma unroll
        for (int m2 = 0; m2 < 3; ++m2) {
            const int ph = j + 8 * m2;
            double v0 = (double)sY[ph][s_loc];
            double v1 = (double)sY[ph + P1c][s_loc];
            icv[m2] = 0.5 * (v0 + v1);
            pc += v0 + v1;
        }
        pc += xor8<1>(pc);
        pc += xor8<2>(pc);
        pc += xor8<4>(pc);
        const double inv_mean48 = 48.0 * nrcp(pc);
        #pragma unroll
        for (int m2 = 0; m2 < 3; ++m2) Icr_own[m2] = icv[m2] * inv_mean48;
    }

    const double mean336     = (sa + sb) * (1.0 / 336.0);
    const double inv_mean336 = nrcp(mean336);
    {
        double rI[3];
        #pragma unroll
        for (int m2 = 0; m2 < 3; ++m2)
            rI[m2] = inv_mean336 * nrcp(Icr_own[m2]);
        #pragma unroll
        for (int m = 0; m < 21; ++m) {
            const int row = j + 8 * m;
            double v0 = (double)sY[row][s_loc];
            double v1 = (double)sY[row + P2c][s_loc];
            sW[row][s_loc] = 0.5 * (v0 + v1) * rI[m % 3];
        }
    }

    double tt0 = 0.5 * ((sa - sb) * (1.0 / (168.0 * 168.0)) +
                        ((double)sY[P2c - 1][s_loc] - (double)sY[0][s_loc]) * (1.0 / 168.0));
    double ss0 = mean336 - 168.5 * tt0;

    double spt0 = ss0 + tt0;      // spt_0
    double snp0 = ss0;            // snew_{-1}

    // ---------------- windowed scan: 64 windows of 8 ----------------
    double xPrev = 0.0, wcPrev = 0.0;
    int wrow = 0, prow = 0, Kb = 0;

#define WIN8(SEL, PSEL, HASD)                                                 \
    {                                                                         \
        double wcv = sW[wrow + j][s_loc];                                     \
        double yv  = (double)sY[Kb + j][s_loc];                               \
        if (HASD) {                                                           \
            Icr_own[PSEL] *= fma(ga_al, xPrev, one_m_ga);                     \
            sW[prow + j][s_loc] = wcPrev * fma(om_al, xPrev, one_m_om);       \
        }                                                                     \
        double iw  = Icr_own[SEL] * wcv;                                      \
        double inv = nrcp1(iw);                                               \
        double aur = (al * yv) * inv;                                         \
        double acc = fma(Pl, spt0, Ql * snp0);                                \
        acc = fma(cf[0], bcast8<0>(aur), acc);                                \
        acc = fma(cf[1], bcast8<1>(aur), acc);                                \
        acc = fma(cf[2], bcast8<2>(aur), acc);                                \
        acc = fma(cf[3], bcast8<3>(aur), acc);                                \
        acc = fma(cf[4], bcast8<4>(aur), acc);                                \
        acc = fma(cf[5], bcast8<5>(aur), acc);                                \
        acc = fma(cf[6], bcast8<6>(aur), acc);                                \
        acc = fma(cf[7], bcast8<7>(aur), acc);                                \
        double s6b = bcast8<6>(acc);                                          \
        double s7b = bcast8<7>(acc);                                          \
        double a6b = bcast8<6>(aur);                                          \
        double a7b = bcast8<7>(aur);                                          \
        double yhat = acc * iw;                                               \
        sY[Kb + j][s_loc] = (float)yhat;                                      \
        double snw = fma(one_m_al, acc, aur);                                 \
        xPrev  = aur * __builtin_amdgcn_rcp(snw);                             \
        wcPrev = wcv;                                                         \
        double snew7 = fma(one_m_al, s7b, a7b);                               \
        double snew6 = fma(one_m_al, s6b, a6b);                               \
        spt0 = fma(one_p_be, snew7, fma(one_m_be, s7b, -snew6));              \
        snp0 = snew7;                                                         \
        prow = wrow;                                                          \
        wrow = (wrow + 8 == P2c) ? 0 : wrow + 8;                              \
        Kb += 8;                                                              \
    }

    WIN8(0, 0, false)        // w0
    WIN8(1, 0, true)         // w1
    WIN8(2, 1, true)         // w2
    for (int k = 0; k < 20; ++k) {   // w3..w62
        WIN8(0, 2, true)
        WIN8(1, 0, true)
        WIN8(2, 1, true)
    }
    WIN8(0, 2, true)         // w63
#undef WIN8

    // drain D' for w63 (SEL was 0; rows prow)
    Icr_own[0] *= fma(ga_al, xPrev, one_m_ga);
    sW[prow + j][s_loc] = wcPrev * fma(om_al, xPrev, one_m_om);

    const double ss_f = snp0;           // snew_511
    const double tt_f = spt0 - snp0;    // tnew_511

    // ---------------- dump f64 state (same ws layout as before) -----------
    wsst[(size_t)(j     ) * NSERIES + g] = Icr_own[0];
    wsst[(size_t)(j + 8 ) * NSERIES + g] = Icr_own[1];
    wsst[(size_t)(j + 16) * NSERIES + g] = Icr_own[2];
    #pragma unroll
    for (int m = 0; m < 21; ++m) {
        const int row = j + 8 * m;
        wsst[(size_t)(P1c + row) * NSERIES + g] = sW[row][s_loc];
    }
    if (j == 0) {
        wsst[(size_t)192 * NSERIES + g] = ss_f;
        wsst[(size_t)193 * NSERIES + g] = tt_f;
        out[OFF_T + bb * NFc + f] = (float)tt_f;
        out[OFF_S + bb * NFc + f] = (float)ss_f;
    }

    // ---------------- coalesced yhat flush ----------------
    __syncthreads();
    float* __restrict__ yho = out + OFF_YH + (size_t)bb * NSTEP * NFc;
    #pragma unroll 4
    for (int i = tid; i < (NSTEP * NFc) / 4; i += 128) {
        ((float4*)yho)[i] = *(const float4*)&sY[i >> 2][(i & 3) * 4];
    }
}

// ---------------------------------------------------------------------------
// Kernel 2: parallel epilogue — fcast + rolled Ic/wc + e = y - yhat.
// item space per bb: [0,336) fc | [336,360) Ic | [360,528) wc | [528,1040) e
// ---------------------------------------------------------------------------
__global__ __launch_bounds__(256)
void dshw_epilogue(const double* __restrict__ ws,
                   const float* __restrict__ yin,
                   float* __restrict__ out)
{
    const int f      = threadIdx.x & 15;
    const int isub   = threadIdx.x >> 4;
    const int bb     = blockIdx.x & 63;
    const int chunk  = blockIdx.x >> 6;
    const int item   = chunk * 16 + isub;
    const int series = bb * NFc + f;

    if (item < MAXH) {
        const int k = item;
        double cb = ws[(size_t)((k + 8) % P1c) * NSERIES + series];
        double cc = ws[(size_t)(P1c + (k + 8) % P2c) * NSERIES + series];
        double ss = ws[(size_t)192 * NSERIES + series];
        double tt = ws[(size_t)193 * NSERIES + series];
        double ca = ss + (double)(k + 1) * tt;
        out[OFF_FC + (bb * MAXH + k) * NFc + f] = (float)(ca * cb * cc);
    } else if (item < MAXH + P1c) {
        const int j = item - MAXH;
        out[OFF_IC + (bb * P1c + j) * NFc + f] =
            (float)ws[(size_t)((j + 8) % P1c) * NSERIES + series];
    } else if (item < MAXH + P1c + P2c) {
        const int j = item - (MAXH + P1c);
        out[OFF_WC + (bb * P2c + j) * NFc + f] =
            (float)ws[(size_t)(P1c + (j + 8) % P2c) * NSERIES + series];
    } else {
        const int s = item - (MAXH + P1c + P2c);       // [0, 512)
        const size_t off = ((size_t)bb * NSTEP + s) * NFc + f;
        float yv = yin[off];
        float yh = out[OFF_YH + off];
        out[OFF_E + off] = yv - yh;
    }
}

// ---------------------------------------------------------------------------
// Fallback (R2 fused kernel, verbatim) — used only if ws is too small.
// ---------------------------------------------------------------------------
__global__ __launch_bounds__(NT, 1)
void dshw_fused(const float* __restrict__ y,
                const float* __restrict__ alphas,
                const float* __restrict__ betas,
                const float* __restrict__ gammas,
                const float* __restrict__ omegas,
                float* __restrict__ out)
{
    __shared__ double sIc[P1c][NT];
    __shared__ double sWc[P2c][NT];

    const int tid = threadIdx.x;
    const int g   = blockIdx.x * NT + tid;
    const int bb  = g >> 4;
    const int f   = g & 15;

    const float* __restrict__ yb = y + (size_t)bb * NSTEP * NFc + f;

    const double al = 1.0 / (1.0 + exp(-(double)alphas[f]));
    const double be = 1.0 / (1.0 + exp(-(double)betas[f]));
    const double ga = 1.0 / (1.0 + exp(-(double)gammas[f]));
    const double om = 1.0 / (1.0 + exp(-(double)omegas[f]));

    double sum48 = 0.0;
    #pragma unroll
    for (int ph = 0; ph < P1c; ++ph) {
        double v0 = (double)yb[ph * NFc];
        double v1 = (double)yb[(ph + P1c) * NFc];
        sIc[ph][tid] = 0.5 * (v0 + v1);
        sum48 += v0 + v1;
    }
    const double inv_mean48 = 48.0 / sum48;
    #pragma unroll
    for (int ph = 0; ph < P1c; ++ph) sIc[ph][tid] *= inv_mean48;

    double sum168a = 0.0, sum168b = 0.0;
    for (int i = 0; i < P2c; ++i) {
        double v0 = (double)yb[i * NFc];
        double v1 = (double)yb[(i + P2c) * NFc];
        sWc[i][tid] = 0.5 * (v0 + v1);
        sum168a += v0;
        sum168b += v1;
    }
    const double mean336 = (sum168a + sum168b) * (1.0 / 336.0);
    for (int i = 0; i < P2c; ++i) {
        sWc[i][tid] = (sWc[i][tid] / mean336) / sIc[i % P1c][tid];
    }

    double tt = 0.5 * ((sum168a - sum168b) * (1.0 / (168.0 * 168.0)) +
                       ((double)yb[(P2c - 1) * NFc] - (double)yb[0]) * (1.0 / 168.0));
    double ss = mean336 - 168.5 * tt;

    float* __restrict__ yh_o = out + OFF_YH + (size_t)bb * NSTEP * NFc + f;
    float* __restrict__ e_o  = out + OFF_E  + (size_t)bb * NSTEP * NFc + f;

    int i1 = 0, i2 = 0;
    int i1p = 2, i2p = 2;

    double Icv0 = sIc[0][tid], Icv1 = sIc[1][tid];
    double wcv0 = sWc[0][tid], wcv1 = sWc[1][tid];
    double yt0 = (double)yb[0 * NFc], yt1 = (double)yb[1 * NFc];
    double yt2 = (double)yb[2 * NFc], yt3 = (double)yb[3 * NFc];

    #pragma unroll 4
    for (int step = 0; step < NSTEP; ++step) {
        double Icv2 = sIc[i1p][tid];
        double wcv2 = sWc[i2p][tid];
        int    pidx = step + 4; pidx = (pidx < NSTEP) ? pidx : (NSTEP - 1);
        double yt4  = (double)yb[pidx * NFc];

        double iw     = Icv0 * wcv0;
        double spt    = ss + tt;
        double yhat   = spt * iw;
        double inv_iw = 1.0 / iw;
        double u      = yt0 * inv_iw;
        double snew   = al * u + (1.0 - al) * spt;
        double tnew   = be * (snew - ss) + (1.0 - be) * tt;
        double q      = yt0 / snew;
        double icn    = ga * (q * (inv_iw * Icv0)) + (1.0 - ga) * Icv0;
        double wcn    = om * (q * (inv_iw * wcv0)) + (1.0 - om) * wcv0;

        sIc[i1][tid] = icn;
        sWc[i2][tid] = wcn;
        yh_o[step * NFc] = (float)yhat;
        e_o[step * NFc]  = (float)(yt0 - yhat);

        ss = snew; tt = tnew;
        Icv0 = Icv1; Icv1 = Icv2;
        wcv0 = wcv1; wcv1 = wcv2;
        yt0 = yt1; yt1 = yt2; yt2 = yt3; yt3 = yt4;
        i1  = (i1  + 1 == P1c) ? 0 : i1  + 1;
        i2  = (i2  + 1 == P2c) ? 0 : i2  + 1;
        i1p = (i1p + 1 == P1c) ? 0 : i1p + 1;
        i2p = (i2p + 1 == P2c) ? 0 : i2p + 1;
    }

    float* __restrict__ fc_o = out + OFF_FC + (size_t)bb * MAXH * NFc + f;
    {
        int k1 = 8, k2 = 8;
        for (int k = 0; k < MAXH; ++k) {
            double cb = sIc[k1][tid];
            double cc = sWc[k2][tid];
            double ca = ss + (double)(k + 1) * tt;
            fc_o[k * NFc] = (float)(ca * cb * cc);
            k1 = (k1 + 1 == P1c) ? 0 : k1 + 1;
            k2 = (k2 + 1 == P2c) ? 0 : k2 + 1;
        }
    }
    {
        float* __restrict__ ic_o = out + OFF_IC + (size_t)bb * P1c * NFc + f;
        int k1 = 8;
        #pragma unroll
        for (int j = 0; j < P1c; ++j) {
            ic_o[j * NFc] = (float)sIc[k1][tid];
            k1 = (k1 + 1 == P1c) ? 0 : k1 + 1;
        }
    }
    {
        float* __restrict__ wc_o = out + OFF_WC + (size_t)bb * P2c * NFc + f;
        int k2 = 8;
        for (int j = 0; j < P2c; ++j) {
            wc_o[j * NFc] = (float)sWc[k2][tid];
            k2 = (k2 + 1 == P2c) ? 0 : k2 + 1;
        }
    }

    out[OFF_T + bb * NFc + f] = (float)tt;
    out[OFF_S + bb * NFc + f] = (float)ss;
}

extern "C" void kernel_launch(void* const* d_in, const int* in_sizes, int n_in,
                              void* d_out, int out_size, void* d_ws, size_t ws_size,
                              hipStream_t stream)
{
    const float* y      = (const float*)d_in[0];
    const float* alphas = (const float*)d_in[1];
    const float* betas  = (const float*)d_in[2];
    const float* gammas = (const float*)d_in[3];
    const float* omegas = (const float*)d_in[4];
    float* out = (float*)d_out;

    if (ws_size >= WS_NEED) {
        double* wsst = (double*)d_ws;
        hipLaunchKernelGGL(dshw_scanw, dim3(BSc), dim3(128), 0, stream,
                           y, alphas, betas, gammas, omegas, wsst, out);
        hipLaunchKernelGGL(dshw_epilogue, dim3(65 * BSc), dim3(256), 0, stream,
                           wsst, y, out);
    } else {
        hipLaunchKernelGGL(dshw_fused, dim3(NSERIES / NT), dim3(NT), 0, stream,
                           y, alphas, betas, gammas, omegas, out);
    }
}

// Round 8
// 83.137 us; speedup vs baseline: 2.4999x; 1.0222x over previous
//
#include <hip/hip_runtime.h>
#include <math.h>

// DSHW — R14: single kernel, zero workspace (R13 scan + in-block epilogue).
// R13 (8-lanes-per-series window scan) took total 134.5 -> 85.0 us; profile
// now dominated by the harness ws-poison fill (~41 us, uncontrollable).
// This round removes everything else around the scan:
//   * epilogue fused into the scan block — all inputs are block-local
//     (Icr in lane regs, final wc in sW, ss/tt in every lane, yhat in sY):
//       - Ic/wc written rolled(+8) straight from regs/LDS
//       - yh + e: coalesced float4 flush (y re-read from global, L2-hot)
//       - fc: staged into freed sY rows 0..335, coalesced float4 flush
//   * ws dump + read + second dispatch deleted; d_ws never touched
// Per-thread epilogue work ~130 elements (R10's failed fusion was 1375/thread
// on 1/4 the threads — that lesson is respected, not contradicted).
// Predicted: dispatch ~21-24 us, total 85 -> ~74-78 us.

#define P1c   24
#define P2c   168
#define NSTEP 512
#define BSc   64
#define NFc   16
#define MAXH  336
#define NSERIES 1024

#define OFF_FC   0
#define OFF_YH   (BSc * MAXH * NFc)
#define OFF_E    (OFF_YH + BSc * NSTEP * NFc)
#define OFF_IC   (OFF_E  + BSc * NSTEP * NFc)
#define OFF_WC   (OFF_IC + BSc * P1c * NFc)
#define OFF_T    (OFF_WC + BSc * P2c * NFc)
#define OFF_S    (OFF_T  + BSc * NFc)

__device__ __forceinline__ double nrcp(double a) {      // 2-NR (init only)
    double x = __builtin_amdgcn_rcp(a);
    x = fma(fma(-a, x, 1.0), x, x);
    x = fma(fma(-a, x, 1.0), x, x);
    return x;
}

__device__ __forceinline__ double nrcp1(double a) {     // 1-NR (p1)
    double x = __builtin_amdgcn_rcp(a);
    x = fma(fma(-a, x, 1.0), x, x);
    return x;
}

// broadcast lane I (0..7) of each 8-lane group: BitMode and=0x18 or=I xor=0
template<int I>
__device__ __forceinline__ double bcast8(double v) {
    constexpr int pat = (I << 5) | 0x18;
    int lo = __builtin_amdgcn_ds_swizzle(__double2loint(v), pat);
    int hi = __builtin_amdgcn_ds_swizzle(__double2hiint(v), pat);
    return __hiloint2double(hi, lo);
}
// xor-butterfly within 8-lane group: and=0x1f or=0 xor=M
template<int M>
__device__ __forceinline__ double xor8(double v) {
    constexpr int pat = (M << 10) | 0x1f;
    int lo = __builtin_amdgcn_ds_swizzle(__double2loint(v), pat);
    int hi = __builtin_amdgcn_ds_swizzle(__double2hiint(v), pat);
    return __hiloint2double(hi, lo);
}

__global__ __launch_bounds__(128, 1)
void dshw_one(const float* __restrict__ y,
              const float* __restrict__ alphas,
              const float* __restrict__ betas,
              const float* __restrict__ gammas,
              const float* __restrict__ omegas,
              float* __restrict__ out)
{
    __shared__ double sW[P2c][NFc];                   // 21 KiB (wc)
    __shared__ double sIc[P1c][NFc];                  // 3 KiB (final Ic, for fc)
    __shared__ __align__(16) float sY[NSTEP][NFc];    // 32 KiB (y -> yhat -> fc)

    const int tid   = threadIdx.x;
    const int s_loc = tid >> 3;          // 0..15  (feature / series-in-block)
    const int j     = tid & 7;           // lane within series group
    const int bb    = blockIdx.x;        // batch row
    const int f     = s_loc;

    // ---------------- stage y into LDS (fully coalesced) ----------------
    const float4* __restrict__ y4 =
        (const float4*)(y + (size_t)bb * NSTEP * NFc);
    #pragma unroll 4
    for (int i = tid; i < (NSTEP * NFc) / 4; i += 128) {
        float4 v = y4[i];
        *(float4*)&sY[i >> 2][(i & 3) * 4] = v;
    }
    __syncthreads();

    const double al = 1.0 / (1.0 + exp(-(double)alphas[f]));
    const double be = 1.0 / (1.0 + exp(-(double)betas[f]));
    const double ga = 1.0 / (1.0 + exp(-(double)gammas[f]));
    const double om = 1.0 / (1.0 + exp(-(double)omegas[f]));
    const double one_m_al = 1.0 - al, one_m_be = 1.0 - be;
    const double one_p_be = 1.0 + be;
    const double one_m_ga = 1.0 - ga, one_m_om = 1.0 - om;
    const double inv_al = nrcp(al);
    const double ga_al  = ga * inv_al;
    const double om_al  = om * inv_al;
    const double A_ = one_p_be * one_m_al + one_m_be;

    // ---------------- per-lane window coefficients ----------------
    // Pl = P[j], Ql = Q[j]; cf[i] = (i<j) ? R[j-1-i] : 0
    double Pl = (j == 0) ? 1.0 : 0.0;
    double Ql = 0.0;
    {
        double p = 1.0, q = 0.0, pn = 0.0, qn = 1.0;
        #pragma unroll
        for (int it = 1; it <= 7; ++it) {
            double p2 = fma(A_, p, -pn);
            double q2 = fma(A_, q, -qn);
            pn = one_m_al * p; qn = one_m_al * q;
            p = p2; q = q2;
            if (j == it) { Pl = p; Ql = q; }
        }
    }
    double R_[8];
    R_[0] = one_p_be;
    {
        double r = one_p_be, rn = 1.0;
        #pragma unroll
        for (int m = 1; m < 8; ++m) {
            double r2 = fma(A_, r, -rn);
            rn = one_m_al * r;
            r = r2;
            R_[m] = r;
        }
    }
    double cf[8];
    #pragma unroll
    for (int i = 0; i < 8; ++i) cf[i] = 0.0;
    #pragma unroll
    for (int i = 0; i < 7; ++i) {
        #pragma unroll
        for (int m = 0; m + i + 1 <= 7; ++m) {
            if (j == i + m + 1) cf[i] = R_[m];
        }
    }

    // ---------------- init (lane-parallel sums + group reduce) -------------
    double pa = 0.0, pb = 0.0;
    #pragma unroll
    for (int m = 0; m < 21; ++m) {
        pa += (double)sY[j + 8 * m][s_loc];
        pb += (double)sY[j + 8 * m + P2c][s_loc];
    }
    pa += xor8<1>(pa); pb += xor8<1>(pb);
    pa += xor8<2>(pa); pb += xor8<2>(pb);
    pa += xor8<4>(pa); pb += xor8<4>(pb);
    const double sa = pa, sb = pb;

    double Icr_own[3];
    {
        double icv[3];
        double pc = 0.0;
        #pragma unroll
        for (int m2 = 0; m2 < 3; ++m2) {
            const int ph = j + 8 * m2;
            double v0 = (double)sY[ph][s_loc];
            double v1 = (double)sY[ph + P1c][s_loc];
            icv[m2] = 0.5 * (v0 + v1);
            pc += v0 + v1;
        }
        pc += xor8<1>(pc);
        pc += xor8<2>(pc);
        pc += xor8<4>(pc);
        const double inv_mean48 = 48.0 * nrcp(pc);
        #pragma unroll
        for (int m2 = 0; m2 < 3; ++m2) Icr_own[m2] = icv[m2] * inv_mean48;
    }

    const double mean336     = (sa + sb) * (1.0 / 336.0);
    const double inv_mean336 = nrcp(mean336);
    {
        double rI[3];
        #pragma unroll
        for (int m2 = 0; m2 < 3; ++m2)
            rI[m2] = inv_mean336 * nrcp(Icr_own[m2]);
        #pragma unroll
        for (int m = 0; m < 21; ++m) {
            const int row = j + 8 * m;
            double v0 = (double)sY[row][s_loc];
            double v1 = (double)sY[row + P2c][s_loc];
            sW[row][s_loc] = 0.5 * (v0 + v1) * rI[m % 3];
        }
    }

    double tt0 = 0.5 * ((sa - sb) * (1.0 / (168.0 * 168.0)) +
                        ((double)sY[P2c - 1][s_loc] - (double)sY[0][s_loc]) * (1.0 / 168.0));
    double ss0 = mean336 - 168.5 * tt0;

    double spt0 = ss0 + tt0;      // spt_0
    double snp0 = ss0;            // snew_{-1}

    // ---------------- windowed scan: 64 windows of 8 ----------------
    double xPrev = 0.0, wcPrev = 0.0;
    int wrow = 0, prow = 0, Kb = 0;

#define WIN8(SEL, PSEL, HASD)                                                 \
    {                                                                         \
        double wcv = sW[wrow + j][s_loc];                                     \
        double yv  = (double)sY[Kb + j][s_loc];                               \
        if (HASD) {                                                           \
            Icr_own[PSEL] *= fma(ga_al, xPrev, one_m_ga);                     \
            sW[prow + j][s_loc] = wcPrev * fma(om_al, xPrev, one_m_om);       \
        }                                                                     \
        double iw  = Icr_own[SEL] * wcv;                                      \
        double inv = nrcp1(iw);                                               \
        double aur = (al * yv) * inv;                                         \
        double acc = fma(Pl, spt0, Ql * snp0);                                \
        acc = fma(cf[0], bcast8<0>(aur), acc);                                \
        acc = fma(cf[1], bcast8<1>(aur), acc);                                \
        acc = fma(cf[2], bcast8<2>(aur), acc);                                \
        acc = fma(cf[3], bcast8<3>(aur), acc);                                \
        acc = fma(cf[4], bcast8<4>(aur), acc);                                \
        acc = fma(cf[5], bcast8<5>(aur), acc);                                \
        acc = fma(cf[6], bcast8<6>(aur), acc);                                \
        acc = fma(cf[7], bcast8<7>(aur), acc);                                \
        double s6b = bcast8<6>(acc);                                          \
        double s7b = bcast8<7>(acc);                                          \
        double a6b = bcast8<6>(aur);                                          \
        double a7b = bcast8<7>(aur);                                          \
        double yhat = acc * iw;                                               \
        sY[Kb + j][s_loc] = (float)yhat;                                      \
        double snw = fma(one_m_al, acc, aur);                                 \
        xPrev  = aur * __builtin_amdgcn_rcp(snw);                             \
        wcPrev = wcv;                                                         \
        double snew7 = fma(one_m_al, s7b, a7b);                               \
        double snew6 = fma(one_m_al, s6b, a6b);                               \
        spt0 = fma(one_p_be, snew7, fma(one_m_be, s7b, -snew6));              \
        snp0 = snew7;                                                         \
        prow = wrow;                                                          \
        wrow = (wrow + 8 == P2c) ? 0 : wrow + 8;                              \
        Kb += 8;                                                              \
    }

    WIN8(0, 0, false)        // w0
    WIN8(1, 0, true)         // w1
    WIN8(2, 1, true)         // w2
    for (int k = 0; k < 20; ++k) {   // w3..w62
        WIN8(0, 2, true)
        WIN8(1, 0, true)
        WIN8(2, 1, true)
    }
    WIN8(0, 2, true)         // w63
#undef WIN8

    // drain D' for w63 (SEL was 0; rows prow)
    Icr_own[0] *= fma(ga_al, xPrev, one_m_ga);
    sW[prow + j][s_loc] = wcPrev * fma(om_al, xPrev, one_m_om);

    const double ss_f = snp0;           // snew_511
    const double tt_f = spt0 - snp0;    // tnew_511

    // ================ fused epilogue (all block-local) ================
    // final Ic into LDS for the fc pass (phases j, j+8, j+16 per lane)
    sIc[j     ][s_loc] = Icr_own[0];
    sIc[j + 8 ][s_loc] = Icr_own[1];
    sIc[j + 16][s_loc] = Icr_own[2];

    // Ic out, rolled +8: out[jj] = Ic[(jj+8)%24]  ->  jj = (p+16)%24
    {
        float* __restrict__ ic_o = out + OFF_IC + (size_t)bb * P1c * NFc + f;
        ic_o[((j + 16) % P1c) * NFc] = (float)Icr_own[0];   // p = j
        ic_o[( j            ) * NFc] = (float)Icr_own[1];   // p = j+8
        ic_o[((j + 8 ) % P1c) * NFc] = (float)Icr_own[2];   // p = j+16
    }
    // wc out, rolled +8: out[jj] = wc[(jj+8)%168] -> jj = (row+160)%168
    {
        float* __restrict__ wc_o = out + OFF_WC + (size_t)bb * P2c * NFc + f;
        #pragma unroll
        for (int m = 0; m < 21; ++m) {
            const int row = j + 8 * m;
            const int jj  = (row >= 8) ? (row - 8) : (row + 160);
            wc_o[jj * NFc] = (float)sW[row][s_loc];
        }
    }
    if (j == 0) {
        out[OFF_T + bb * NFc + f] = (float)tt_f;
        out[OFF_S + bb * NFc + f] = (float)ss_f;
    }

    // yhat + e flush (coalesced float4; y re-read from global, L2-hot)
    __syncthreads();
    {
        float* __restrict__ yho = out + OFF_YH + (size_t)bb * NSTEP * NFc;
        float* __restrict__ eo  = out + OFF_E  + (size_t)bb * NSTEP * NFc;
        #pragma unroll 4
        for (int i = tid; i < (NSTEP * NFc) / 4; i += 128) {
            float4 yh4 = *(const float4*)&sY[i >> 2][(i & 3) * 4];
            float4 yv4 = y4[i];
            ((float4*)yho)[i] = yh4;
            float4 ev;
            ev.x = yv4.x - yh4.x; ev.y = yv4.y - yh4.y;
            ev.z = yv4.z - yh4.z; ev.w = yv4.w - yh4.w;
            ((float4*)eo)[i] = ev;
        }
    }
    __syncthreads();

    // fc stage into freed sY rows 0..335: lane j does k = j, j+8, ..., j+328
    {
        int p1i = j + 8;                 // (k+8) % 24, rolling
        int p2i = j + 8;                 // (k+8) % 168, rolling
        #pragma unroll 6
        for (int m = 0; m < 42; ++m) {
            const int k = j + 8 * m;
            double cb = sIc[p1i][s_loc];
            double cc = sW[p2i][s_loc];
            double ca = fma((double)(k + 1), tt_f, ss_f);
            sY[k][s_loc] = (float)(ca * cb * cc);
            p1i += 8; p1i = (p1i >= P1c) ? (p1i - P1c) : p1i;
            p2i += 8; p2i = (p2i >= P2c) ? (p2i - P2c) : p2i;
        }
    }
    __syncthreads();

    // fc flush (coalesced float4)
    {
        float* __restrict__ fco = out + OFF_FC + (size_t)bb * MAXH * NFc;
        #pragma unroll 4
        for (int i = tid; i < (MAXH * NFc) / 4; i += 128) {
            ((float4*)fco)[i] = *(const float4*)&sY[i >> 2][(i & 3) * 4];
        }
    }
}

extern "C" void kernel_launch(void* const* d_in, const int* in_sizes, int n_in,
                              void* d_out, int out_size, void* d_ws, size_t ws_size,
                              hipStream_t stream)
{
    const float* y      = (const float*)d_in[0];
    const float* alphas = (const float*)d_in[1];
    const float* betas  = (const float*)d_in[2];
    const float* gammas = (const float*)d_in[3];
    const float* omegas = (const float*)d_in[4];
    float* out = (float*)d_out;

    hipLaunchKernelGGL(dshw_one, dim3(BSc), dim3(128), 0, stream,
                       y, alphas, betas, gammas, omegas, out);
}